// Round 1
// baseline (917.654 us; speedup 1.0000x reference)
//
#include <hip/hip_runtime.h>
#include <cstdint>
#include <cstddef>

#define N_NODES 100000
#define N_EDGES 3200000
#define N_FEAT  512
#define HIDDEN  16
#define N_LABELS 64

#define NODE_BLOCKS 391          // ceil(100000/256)
#define EDGE_BLOCKS 12500        // 3200000/256

// ---------------- workspace layout (bytes) ----------------
// deg   : N int      @ 0
// dis   : N float    @ 512K
// cur   : N int      @ 1024K   (exclusive offsets; after scatter cur[n] == offs[n+1])
// bsum  : 391 int    @ 1536K
// bscan : 391 int    @ 1544K
// csr   : E int      @ 2M      (12.8 MB)
// xw/z  : N*16 float @ 15M     (6.4 MB)   xw1 for layer1, reused as z for layer2
// h     : N*16 float @ 23M     (6.4 MB)
// total ~29.2 MB
static const size_t O_DEG   = 0;
static const size_t O_DIS   = 512u << 10;
static const size_t O_CUR   = 1024u << 10;
static const size_t O_BSUM  = 1536u << 10;
static const size_t O_BSCAN = 1544u << 10;
static const size_t O_CSR   = 2u << 20;
static const size_t O_XW    = 15u << 20;
static const size_t O_H     = 23u << 20;

// ---------------- graph preprocessing ----------------

__global__ __launch_bounds__(256) void k_deg(const int* __restrict__ frm,
                                             const int* __restrict__ to,
                                             int* __restrict__ deg) {
    int e = blockIdx.x * 256 + threadIdx.x;
    if (e < N_EDGES) {
        int f = frm[e], t = to[e];
        if (f != t) atomicAdd(&deg[t], 1);
    }
}

__global__ __launch_bounds__(256) void k_dis(const int* __restrict__ deg,
                                             float* __restrict__ dis) {
    int n = blockIdx.x * 256 + threadIdx.x;
    if (n < N_NODES) dis[n] = rsqrtf((float)deg[n] + 1.0f);
}

// block-wise exclusive scan (Hillis-Steele), block sums out
__global__ __launch_bounds__(256) void k_scan1(const int* __restrict__ deg,
                                               int* __restrict__ cur,
                                               int* __restrict__ bsum) {
    __shared__ int s[256];
    int t = threadIdx.x;
    int i = blockIdx.x * 256 + t;
    int v = (i < N_NODES) ? deg[i] : 0;
    s[t] = v; __syncthreads();
    #pragma unroll
    for (int off = 1; off < 256; off <<= 1) {
        int a = (t >= off) ? s[t - off] : 0;
        __syncthreads();
        s[t] += a;
        __syncthreads();
    }
    if (i < N_NODES) cur[i] = s[t] - v;       // exclusive within block
    if (t == 255) bsum[blockIdx.x] = s[255];  // block total
}

__global__ __launch_bounds__(512) void k_scan2(const int* __restrict__ bsum,
                                               int* __restrict__ bscan, int nb) {
    __shared__ int s[512];
    int t = threadIdx.x;
    int v = (t < nb) ? bsum[t] : 0;
    s[t] = v; __syncthreads();
    #pragma unroll
    for (int off = 1; off < 512; off <<= 1) {
        int a = (t >= off) ? s[t - off] : 0;
        __syncthreads();
        s[t] += a;
        __syncthreads();
    }
    if (t < nb) bscan[t] = s[t] - v;          // exclusive
}

__global__ __launch_bounds__(256) void k_scan3(int* __restrict__ cur,
                                               const int* __restrict__ bscan) {
    int i = blockIdx.x * 256 + threadIdx.x;
    if (i < N_NODES) cur[i] += bscan[blockIdx.x];
}

// scatter non-self edges into CSR by destination; afterwards cur[n] == offs[n+1]
__global__ __launch_bounds__(256) void k_scatter(const int* __restrict__ frm,
                                                 const int* __restrict__ to,
                                                 int* __restrict__ cur,
                                                 int* __restrict__ csr) {
    int e = blockIdx.x * 256 + threadIdx.x;
    if (e < N_EDGES) {
        int f = frm[e], t = to[e];
        if (f != t) {
            int p = atomicAdd(&cur[t], 1);
            csr[p] = f;
        }
    }
}

// ---------------- xw = x @ W1  (N x 512) @ (512 x 16) ----------------
// 256 threads = 256 nodes per block, node-per-thread.
// x staged in LDS with pad 33: compute-read bank (t+k)%32, staging-write
// bank ((t>>3)+4*(t&7)+i)%32 -- both exactly 2 lanes/bank (free, m136).
// W1 read at wave-uniform address (scalarizable / L1 broadcast).
#define KT 32
__global__ __launch_bounds__(256) void k_gemm1(const float* __restrict__ x,
                                               const float* __restrict__ W1,
                                               float* __restrict__ xw) {
    __shared__ float xs[256 * 33];
    const int t = threadIdx.x;
    const int base = blockIdx.x * 256;
    float acc[HIDDEN];
    #pragma unroll
    for (int j = 0; j < HIDDEN; ++j) acc[j] = 0.f;

    const int pr = t >> 3;        // row sub-index within each 32-row pass
    const int pc = (t & 7) * 4;   // col (floats)

    for (int kt = 0; kt < N_FEAT / KT; ++kt) {
        __syncthreads();   // previous tile's reads complete before overwrite
        #pragma unroll
        for (int p = 0; p < 8; ++p) {
            int r = p * 32 + pr;
            int n = base + r;
            float4 v = make_float4(0.f, 0.f, 0.f, 0.f);
            if (n < N_NODES)
                v = *(const float4*)(x + (size_t)n * N_FEAT + kt * KT + pc);
            xs[r * 33 + pc + 0] = v.x;
            xs[r * 33 + pc + 1] = v.y;
            xs[r * 33 + pc + 2] = v.z;
            xs[r * 33 + pc + 3] = v.w;
        }
        __syncthreads();
        #pragma unroll
        for (int kk = 0; kk < KT; ++kk) {
            float xv = xs[t * 33 + kk];
            const float4* wr = (const float4*)(W1 + ((kt * KT + kk) << 4));
            float4 wa = wr[0], wb = wr[1], wc = wr[2], wd = wr[3];
            acc[ 0] = fmaf(xv, wa.x, acc[ 0]);
            acc[ 1] = fmaf(xv, wa.y, acc[ 1]);
            acc[ 2] = fmaf(xv, wa.z, acc[ 2]);
            acc[ 3] = fmaf(xv, wa.w, acc[ 3]);
            acc[ 4] = fmaf(xv, wb.x, acc[ 4]);
            acc[ 5] = fmaf(xv, wb.y, acc[ 5]);
            acc[ 6] = fmaf(xv, wb.z, acc[ 6]);
            acc[ 7] = fmaf(xv, wb.w, acc[ 7]);
            acc[ 8] = fmaf(xv, wc.x, acc[ 8]);
            acc[ 9] = fmaf(xv, wc.y, acc[ 9]);
            acc[10] = fmaf(xv, wc.z, acc[10]);
            acc[11] = fmaf(xv, wc.w, acc[11]);
            acc[12] = fmaf(xv, wd.x, acc[12]);
            acc[13] = fmaf(xv, wd.y, acc[13]);
            acc[14] = fmaf(xv, wd.z, acc[14]);
            acc[15] = fmaf(xv, wd.w, acc[15]);
        }
    }
    int n = base + t;
    if (n < N_NODES) {
        float* o = xw + (size_t)n * HIDDEN;
        #pragma unroll
        for (int j = 0; j < HIDDEN; ++j) o[j] = acc[j];
    }
}

// ---------------- aggregation in 16-dim space ----------------
// out[n] = relu?( dis[n]*sum_{f in N(n)} dis[f]*xw[f] + dis[n]^2*xw[n] + bias )
// 16 lanes per node (lane = feature j): csr/dis loads broadcast, xw gather
// is a coalesced 64B read per edge. cur[] holds end-offsets post-scatter.
__global__ __launch_bounds__(256) void k_agg(const float* __restrict__ xw,
                                             const int* __restrict__ cur,
                                             const int* __restrict__ csr,
                                             const float* __restrict__ dis,
                                             const float* __restrict__ bias,
                                             float* __restrict__ out,
                                             int do_relu) {
    int t = threadIdx.x;
    int j = t & 15;
    int n = blockIdx.x * 16 + (t >> 4);
    int s0 = (n == 0) ? 0 : cur[n - 1];
    int e0 = cur[n];
    float acc = 0.f, acc2 = 0.f;
    int i = s0;
    for (; i + 2 <= e0; i += 2) {          // 2x unroll for load ILP
        int f0 = csr[i], f1 = csr[i + 1];
        float d0 = dis[f0], d1 = dis[f1];
        acc  = fmaf(d0, xw[(size_t)f0 * HIDDEN + j], acc);
        acc2 = fmaf(d1, xw[(size_t)f1 * HIDDEN + j], acc2);
    }
    if (i < e0) {
        int f0 = csr[i];
        acc = fmaf(dis[f0], xw[(size_t)f0 * HIDDEN + j], acc);
    }
    acc += acc2;
    float dn = dis[n];
    float v = fmaf(acc, dn, xw[(size_t)n * HIDDEN + j] * dn * dn);
    if (bias) v += bias[j];
    if (do_relu) v = fmaxf(v, 0.f);
    out[(size_t)n * HIDDEN + j] = v;
}

// ---------------- logits = z @ W2 + b2, fused log_softmax ----------------
// one wave per node, lane = label. W2 reads coalesced 256B/k, wave-wide
// shfl_xor reductions for max / logsumexp, 256B coalesced output.
__global__ __launch_bounds__(256) void k_out(const float* __restrict__ z,
                                             const float* __restrict__ W2,
                                             const float* __restrict__ b2,
                                             float* __restrict__ out) {
    int gt = blockIdx.x * 256 + threadIdx.x;
    int n = gt >> 6;
    int j = gt & 63;
    float acc = b2[j];
    const float* zr = z + (size_t)n * HIDDEN;
    #pragma unroll
    for (int k = 0; k < HIDDEN; ++k)
        acc = fmaf(zr[k], W2[k * N_LABELS + j], acc);
    float m = acc;
    #pragma unroll
    for (int off = 32; off > 0; off >>= 1)
        m = fmaxf(m, __shfl_xor(m, off, 64));
    float ex = __expf(acc - m);
    float sum = ex;
    #pragma unroll
    for (int off = 32; off > 0; off >>= 1)
        sum += __shfl_xor(sum, off, 64);
    out[(size_t)n * N_LABELS + j] = acc - m - __logf(sum);
}

// ---------------- launch ----------------
extern "C" void kernel_launch(void* const* d_in, const int* in_sizes, int n_in,
                              void* d_out, int out_size, void* d_ws, size_t ws_size,
                              hipStream_t stream) {
    const float* x  = (const float*)d_in[0];
    const int*   ei = (const int*)d_in[1];
    const float* W1 = (const float*)d_in[2];
    const float* b1 = (const float*)d_in[3];
    const float* W2 = (const float*)d_in[4];
    const float* b2 = (const float*)d_in[5];
    float* out = (float*)d_out;
    char*  ws  = (char*)d_ws;

    int*   deg   = (int*)(ws + O_DEG);
    float* dis   = (float*)(ws + O_DIS);
    int*   cur   = (int*)(ws + O_CUR);
    int*   bsum  = (int*)(ws + O_BSUM);
    int*   bscan = (int*)(ws + O_BSCAN);
    int*   csr   = (int*)(ws + O_CSR);
    float* xw    = (float*)(ws + O_XW);   // xw1, later reused as z
    float* h     = (float*)(ws + O_H);

    const int* frm = ei;
    const int* to  = ei + N_EDGES;

    hipMemsetAsync(deg, 0, N_NODES * sizeof(int), stream);

    k_deg    <<<EDGE_BLOCKS, 256, 0, stream>>>(frm, to, deg);
    k_dis    <<<NODE_BLOCKS, 256, 0, stream>>>(deg, dis);
    k_scan1  <<<NODE_BLOCKS, 256, 0, stream>>>(deg, cur, bsum);
    k_scan2  <<<1, 512, 0, stream>>>(bsum, bscan, NODE_BLOCKS);
    k_scan3  <<<NODE_BLOCKS, 256, 0, stream>>>(cur, bscan);
    k_scatter<<<EDGE_BLOCKS, 256, 0, stream>>>(frm, to, cur, csr);

    k_gemm1  <<<NODE_BLOCKS, 256, 0, stream>>>(x, W1, xw);
    k_agg    <<<N_NODES / 16, 256, 0, stream>>>(xw, cur, csr, dis, b1, h, 1);
    k_agg    <<<N_NODES / 16, 256, 0, stream>>>(h, cur, csr, dis, nullptr, xw, 0);
    k_out    <<<N_NODES / 4, 256, 0, stream>>>(xw, W2, b2, out);
}